// Round 1
// baseline (344.544 us; speedup 1.0000x reference)
//
#include <hip/hip_runtime.h>
#include <hip/hip_bf16.h>
#include <cstdint>

// ---------------------------------------------------------------------------
// LocalWindowTransformer: windowed MHA, B=4 L=4096 H=1024 NH=16 hd=64 P=128
// Pipeline: cvt(x,Win,Wout)->bf16 ; qkv = x@Win^T+b ; per-(win,head) attn ;
//           out = o@Wout^T+b (fp32)
// All GEMMs: C[m,n] = sum_k A[m,k]*B[n,k]  (B given row-major [N,K] = B^T form)
// MFMA 16x16x32 bf16 layouts (HW-verified per guide):
//   A-frag: lane holds A[m=lane&15][k=(lane>>4)*8+j], j=0..7
//   B-frag: lane holds B_hw[k=(lane>>4)*8+j][n=lane&15]  (== Bmat[n][k] loaded
//           identically to A from the [N,K] tile)
//   C/D   : reg r holds C[row=(lane>>4)*4+r][col=lane&15]
// ---------------------------------------------------------------------------

typedef __bf16 bf16_t;
typedef __bf16 bf16x8 __attribute__((ext_vector_type(8)));
typedef float  floatx4 __attribute__((ext_vector_type(4)));

#define MFMA_16x16x32(A, B, C) __builtin_amdgcn_mfma_f32_16x16x32_bf16(A, B, C, 0, 0, 0)

// async global->LDS, 16B per lane; LDS dest = wave-uniform base + lane*16
__device__ __forceinline__ void gld_lds16(const bf16_t* g, bf16_t* l) {
  __builtin_amdgcn_global_load_lds(
      (__attribute__((address_space(1))) void*)(void*)(g),
      (__attribute__((address_space(3))) void*)(l), 16, 0, 0);
}

// ---------------------------------------------------------------------------
__global__ void cvt_f32_to_bf16(const float* __restrict__ src,
                                bf16_t* __restrict__ dst, int n8) {
  int i = blockIdx.x * blockDim.x + threadIdx.x;
  if (i >= n8) return;
  const float4* s4 = (const float4*)src;
  float4 a = s4[2 * (size_t)i];
  float4 b = s4[2 * (size_t)i + 1];
  bf16x8 o;
  o[0] = (bf16_t)a.x; o[1] = (bf16_t)a.y; o[2] = (bf16_t)a.z; o[3] = (bf16_t)a.w;
  o[4] = (bf16_t)b.x; o[5] = (bf16_t)b.y; o[6] = (bf16_t)b.z; o[7] = (bf16_t)b.w;
  *(bf16x8*)(dst + (size_t)i * 8) = o;
}

// ---------------------------------------------------------------------------
// m97-style GEMM: BM=BN=128, BK=32, 256 threads (4 waves, 2x2 of 64x64),
// single-buffered LDS staged via global_load_lds dwordx4.
template <bool F32OUT>
__global__ __launch_bounds__(256, 2) void gemm_bt(
    const bf16_t* __restrict__ A, const bf16_t* __restrict__ Bm,
    const float* __restrict__ bias, void* __restrict__ Cp,
    int M, int N, int K) {
  __shared__ bf16_t As[128 * 32];
  __shared__ bf16_t Bs[128 * 32];
  const int tid  = threadIdx.x;
  const int lane = tid & 63;
  const int wave = tid >> 6;
  const int n16  = lane & 15;
  const int q4   = lane >> 4;
  const int wm   = (wave >> 1) * 64;
  const int wn   = (wave & 1) * 64;
  const int m0   = blockIdx.y * 128;
  const int n0   = blockIdx.x * 128;

  floatx4 acc[4][4] = {};

  for (int k0 = 0; k0 < K; k0 += 32) {
    __syncthreads();  // prior iter's ds_reads complete before overwrite
#pragma unroll
    for (int it = 0; it < 2; ++it) {
      const int ch = it * 256 + wave * 64 + lane;  // 512 chunks of 8 bf16
      const int r = ch >> 2, c = (ch & 3) * 8;
      bf16_t* ldsbase = (it == 0) ? nullptr : nullptr;  // (see below)
      gld_lds16(A + (size_t)(m0 + r) * K + k0 + c,
                As + (size_t)(it * 256 + wave * 64) * 8);
      gld_lds16(Bm + (size_t)(n0 + r) * K + k0 + c,
                Bs + (size_t)(it * 256 + wave * 64) * 8);
    }
    __syncthreads();  // implies vmcnt(0): staging visible

    bf16x8 af[4], bf[4];
#pragma unroll
    for (int i = 0; i < 4; ++i)
      af[i] = *(const bf16x8*)&As[(wm + i * 16 + n16) * 32 + q4 * 8];
#pragma unroll
    for (int j = 0; j < 4; ++j)
      bf[j] = *(const bf16x8*)&Bs[(wn + j * 16 + n16) * 32 + q4 * 8];
#pragma unroll
    for (int i = 0; i < 4; ++i)
#pragma unroll
      for (int j = 0; j < 4; ++j)
        acc[i][j] = MFMA_16x16x32(af[i], bf[j], acc[i][j]);
  }

#pragma unroll
  for (int i = 0; i < 4; ++i)
#pragma unroll
    for (int j = 0; j < 4; ++j) {
      const int col = n0 + wn + j * 16 + n16;
      const float b = bias[col];
#pragma unroll
      for (int r = 0; r < 4; ++r) {
        const int row = m0 + wm + i * 16 + q4 * 4 + r;
        const float v = acc[i][j][r] + b;
        if (F32OUT)
          ((float*)Cp)[(size_t)row * N + col] = v;
        else
          ((bf16_t*)Cp)[(size_t)row * N + col] = (bf16_t)v;
      }
    }
}

// ---------------------------------------------------------------------------
// Attention: one 256-thread block per (window, head). q,k,v: [128,64] bf16.
// LDS: q,k,v row-major padded to 72 elems/row (breaks 16-way bank conflict on
// fragment reads -> 2-way, free). P [128][136] bf16 overlaps q+k region after
// the S-phase barrier. Wave w owns S/O rows [32w, 32w+32).
__global__ __launch_bounds__(256, 2) void attn_win(
    const bf16_t* __restrict__ qkv, bf16_t* __restrict__ o) {
  __shared__ bf16_t smem[3 * 128 * 72];  // 55296 B
  bf16_t* qs = smem;
  bf16_t* ks_ = smem + 128 * 72;
  bf16_t* vs = smem + 2 * 128 * 72;
  bf16_t* Ps = smem;  // [128][136], max idx 17399 < 18432 (vs untouched)

  const int wid  = blockIdx.x >> 4;   // window 0..127
  const int h    = blockIdx.x & 15;   // head
  const int tid  = threadIdx.x;
  const int lane = tid & 63;
  const int wave = tid >> 6;
  const int n16  = lane & 15;
  const int q4   = lane >> 4;

  // ---- stage q,k,v (coalesced 16B global loads, padded LDS writes)
  const bf16_t* gq = qkv + (size_t)wid * 128 * 3072 + h * 64;
#pragma unroll
  for (int it = 0; it < 4; ++it) {
    const int c = it * 256 + tid;         // 1024 chunks of 8
    const int p = c >> 3, col = (c & 7) * 8;
    const size_t go = (size_t)p * 3072 + col;
    *(bf16x8*)&qs[p * 72 + col]  = *(const bf16x8*)(gq + go);
    *(bf16x8*)&ks_[p * 72 + col] = *(const bf16x8*)(gq + 1024 + go);
    *(bf16x8*)&vs[p * 72 + col]  = *(const bf16x8*)(gq + 2048 + go);
  }
  __syncthreads();

  // ---- S = q k^T  (rows [32w,32w+32) x 128 cols, K=64)
  floatx4 sacc[2][8] = {};
#pragma unroll
  for (int ks = 0; ks < 2; ++ks) {
    bf16x8 aq[2];
#pragma unroll
    for (int i = 0; i < 2; ++i)
      aq[i] = *(const bf16x8*)&qs[(wave * 32 + i * 16 + n16) * 72 + ks * 32 + q4 * 8];
#pragma unroll
    for (int j = 0; j < 8; ++j) {
      bf16x8 bk = *(const bf16x8*)&ks_[(j * 16 + n16) * 72 + ks * 32 + q4 * 8];
      sacc[0][j] = MFMA_16x16x32(aq[0], bk, sacc[0][j]);
      sacc[1][j] = MFMA_16x16x32(aq[1], bk, sacc[1][j]);
    }
  }
  __syncthreads();  // all q/k reads done; P may overwrite their LDS

  // ---- softmax over each row (lane's 8 cols, then 16-lane xor-reduce)
  const float scale = 0.125f;  // 1/sqrt(64)
#pragma unroll
  for (int i = 0; i < 2; ++i) {
#pragma unroll
    for (int r = 0; r < 4; ++r) {
      float vals[8];
      float mx = -1e30f;
#pragma unroll
      for (int j = 0; j < 8; ++j) {
        vals[j] = sacc[i][j][r] * scale;
        mx = fmaxf(mx, vals[j]);
      }
      for (int m = 1; m < 16; m <<= 1) mx = fmaxf(mx, __shfl_xor(mx, m, 64));
      float s = 0.f;
#pragma unroll
      for (int j = 0; j < 8; ++j) {
        vals[j] = __expf(vals[j] - mx);
        s += vals[j];
      }
      for (int m = 1; m < 16; m <<= 1) s += __shfl_xor(s, m, 64);
      const float inv = 1.0f / s;
      const int prow = wave * 32 + i * 16 + q4 * 4 + r;
#pragma unroll
      for (int j = 0; j < 8; ++j)
        Ps[prow * 136 + j * 16 + n16] = (bf16_t)(vals[j] * inv);
    }
  }
  __syncthreads();

  // ---- O = P V  (rows [32w,32w+32) x 64 cols, K=128)
  floatx4 oacc[2][4] = {};
#pragma unroll
  for (int kk = 0; kk < 4; ++kk) {
    bf16x8 ap[2];
#pragma unroll
    for (int i = 0; i < 2; ++i)
      ap[i] = *(const bf16x8*)&Ps[(wave * 32 + i * 16 + n16) * 136 + kk * 32 + q4 * 8];
#pragma unroll
    for (int j = 0; j < 4; ++j) {
      bf16x8 bv;
#pragma unroll
      for (int t = 0; t < 8; ++t)
        bv[t] = vs[(kk * 32 + q4 * 8 + t) * 72 + j * 16 + n16];
      oacc[0][j] = MFMA_16x16x32(ap[0], bv, oacc[0][j]);
      oacc[1][j] = MFMA_16x16x32(ap[1], bv, oacc[1][j]);
    }
  }

  // ---- write O in merged-head layout [token][h*64+d]
  bf16_t* go = o + (size_t)wid * 128 * 1024 + h * 64;
#pragma unroll
  for (int i = 0; i < 2; ++i)
#pragma unroll
    for (int j = 0; j < 4; ++j)
#pragma unroll
      for (int r = 0; r < 4; ++r) {
        const int row = wave * 32 + i * 16 + q4 * 4 + r;
        go[(size_t)row * 1024 + j * 16 + n16] = (bf16_t)oacc[i][j][r];
      }
}

// ---------------------------------------------------------------------------
extern "C" void kernel_launch(void* const* d_in, const int* in_sizes, int n_in,
                              void* d_out, int out_size, void* d_ws, size_t ws_size,
                              hipStream_t stream) {
  const float* x    = (const float*)d_in[0];
  const float* Win  = (const float*)d_in[1];   // [3072,1024]
  const float* bin  = (const float*)d_in[2];   // [3072]
  const float* Wout = (const float*)d_in[3];   // [1024,1024]
  const float* bout = (const float*)d_in[4];   // [1024]
  float* out = (float*)d_out;

  const size_t M = 16384, H = 1024, H3 = 3072;

  // workspace layout (136 MB): xb | Winb | Woutb | qkv ; ob aliases xb
  bf16_t* xb    = (bf16_t*)d_ws;        // M*H
  bf16_t* Winb  = xb + M * H;           // H3*H
  bf16_t* Woutb = Winb + H3 * H;        // H*H
  bf16_t* qkv   = Woutb + H * H;        // M*H3
  bf16_t* ob    = xb;                   // reuse: xb dead after gemm1

  cvt_f32_to_bf16<<<dim3((unsigned)(M * H / 8 / 256)), 256, 0, stream>>>(x, xb, (int)(M * H / 8));
  cvt_f32_to_bf16<<<dim3((unsigned)(H3 * H / 8 / 256)), 256, 0, stream>>>(Win, Winb, (int)(H3 * H / 8));
  cvt_f32_to_bf16<<<dim3((unsigned)(H * H / 8 / 256)), 256, 0, stream>>>(Wout, Woutb, (int)(H * H / 8));

  gemm_bt<false><<<dim3((unsigned)(H3 / 128), (unsigned)(M / 128)), 256, 0, stream>>>(
      xb, Winb, bin, qkv, (int)M, (int)H3, (int)H);

  attn_win<<<dim3(2048), 256, 0, stream>>>(qkv, ob);

  gemm_bt<true><<<dim3((unsigned)(H / 128), (unsigned)(M / 128)), 256, 0, stream>>>(
      ob, Woutb, bout, out, (int)M, (int)H, (int)H);
}

// Round 2
// 333.734 us; speedup vs baseline: 1.0324x; 1.0324x over previous
//
#include <hip/hip_runtime.h>
#include <hip/hip_bf16.h>
#include <cstdint>

// ---------------------------------------------------------------------------
// LocalWindowTransformer: windowed MHA, B=4 L=4096 H=1024 NH=16 hd=64 P=128
// R2: fused per-(window,head) QKV-projection + attention (kills the 200 MB
//     qkv HBM round-trip and the scalar V-fragment LDS reads), then
//     out = o @ Wout^T + b (fp32) via the m97-style GEMM.
// MFMA 16x16x32 bf16 layouts (HW-verified per guide):
//   A-frag: lane holds A[m=lane&15][k=(lane>>4)*8+j], j=0..7
//   B-frag: lane holds B_hw[k=(lane>>4)*8+j][n=lane&15]
//   C/D   : reg r holds C[row=(lane>>4)*4+r][col=lane&15]
// ---------------------------------------------------------------------------

typedef __bf16 bf16_t;
typedef __bf16 bf16x8 __attribute__((ext_vector_type(8)));
typedef __bf16 bf16x4 __attribute__((ext_vector_type(4)));
typedef float  floatx4 __attribute__((ext_vector_type(4)));

#define MFMA_16x16x32(A, B, C) __builtin_amdgcn_mfma_f32_16x16x32_bf16(A, B, C, 0, 0, 0)

// async global->LDS, 16B per lane; LDS dest = wave-uniform base + lane*16
__device__ __forceinline__ void gld_lds16(const bf16_t* g, bf16_t* l) {
  __builtin_amdgcn_global_load_lds(
      (__attribute__((address_space(1))) void*)(void*)(g),
      (__attribute__((address_space(3))) void*)(l), 16, 0, 0);
}

// ---------------------------------------------------------------------------
__global__ void cvt_f32_to_bf16(const float* __restrict__ src,
                                bf16_t* __restrict__ dst, int n8) {
  int i = blockIdx.x * blockDim.x + threadIdx.x;
  if (i >= n8) return;
  const float4* s4 = (const float4*)src;
  float4 a = s4[2 * (size_t)i];
  float4 b = s4[2 * (size_t)i + 1];
  bf16x8 o;
  o[0] = (bf16_t)a.x; o[1] = (bf16_t)a.y; o[2] = (bf16_t)a.z; o[3] = (bf16_t)a.w;
  o[4] = (bf16_t)b.x; o[5] = (bf16_t)b.y; o[6] = (bf16_t)b.z; o[7] = (bf16_t)b.w;
  *(bf16x8*)(dst + (size_t)i * 8) = o;
}

// Repack Win [3072,1024] f32 -> Wpk [16 heads][192 rows][1024] bf16,
// rows per head: q(h*64..), k(1024+h*64..), v(2048+h*64..)
__global__ void cvt_repack_win(const float* __restrict__ Win,
                               bf16_t* __restrict__ Wpk) {
  const int dr = blockIdx.x;              // packed row 0..3071
  const int head = dr / 192, s = dr - head * 192;
  const int src = (s < 64) ? head * 64 + s
                : (s < 128) ? 1024 + head * 64 + (s - 64)
                            : 2048 + head * 64 + (s - 128);
  const float4* srow = (const float4*)(Win + (size_t)src * 1024);
  const int i = threadIdx.x;              // 128 threads x 8 elems
  float4 a = srow[2 * i];
  float4 b = srow[2 * i + 1];
  bf16x8 o;
  o[0] = (bf16_t)a.x; o[1] = (bf16_t)a.y; o[2] = (bf16_t)a.z; o[3] = (bf16_t)a.w;
  o[4] = (bf16_t)b.x; o[5] = (bf16_t)b.y; o[6] = (bf16_t)b.z; o[7] = (bf16_t)b.w;
  *(bf16x8*)(Wpk + (size_t)dr * 1024 + i * 8) = o;
}

// ---------------------------------------------------------------------------
// m97-style GEMM (used for the out-projection): BM=BN=128, BK=32, 256 thr.
template <bool F32OUT>
__global__ __launch_bounds__(256, 2) void gemm_bt(
    const bf16_t* __restrict__ A, const bf16_t* __restrict__ Bm,
    const float* __restrict__ bias, void* __restrict__ Cp,
    int M, int N, int K) {
  __shared__ bf16_t As[128 * 32];
  __shared__ bf16_t Bs[128 * 32];
  const int tid  = threadIdx.x;
  const int lane = tid & 63;
  const int wave = tid >> 6;
  const int n16  = lane & 15;
  const int q4   = lane >> 4;
  const int wm   = (wave >> 1) * 64;
  const int wn   = (wave & 1) * 64;
  const int m0   = blockIdx.y * 128;
  const int n0   = blockIdx.x * 128;

  floatx4 acc[4][4] = {};

  for (int k0 = 0; k0 < K; k0 += 32) {
    __syncthreads();
#pragma unroll
    for (int it = 0; it < 2; ++it) {
      const int ch = it * 256 + wave * 64 + lane;  // 512 chunks of 8 bf16
      const int r = ch >> 2, c = (ch & 3) * 8;
      gld_lds16(A + (size_t)(m0 + r) * K + k0 + c,
                As + (size_t)(it * 256 + wave * 64) * 8);
      gld_lds16(Bm + (size_t)(n0 + r) * K + k0 + c,
                Bs + (size_t)(it * 256 + wave * 64) * 8);
    }
    __syncthreads();

    bf16x8 af[4], bfr[4];
#pragma unroll
    for (int i = 0; i < 4; ++i)
      af[i] = *(const bf16x8*)&As[(wm + i * 16 + n16) * 32 + q4 * 8];
#pragma unroll
    for (int j = 0; j < 4; ++j)
      bfr[j] = *(const bf16x8*)&Bs[(wn + j * 16 + n16) * 32 + q4 * 8];
#pragma unroll
    for (int i = 0; i < 4; ++i)
#pragma unroll
      for (int j = 0; j < 4; ++j)
        acc[i][j] = MFMA_16x16x32(af[i], bfr[j], acc[i][j]);
  }

#pragma unroll
  for (int i = 0; i < 4; ++i)
#pragma unroll
    for (int j = 0; j < 4; ++j) {
      const int col = n0 + wn + j * 16 + n16;
      const float b = bias[col];
#pragma unroll
      for (int r = 0; r < 4; ++r) {
        const int row = m0 + wm + i * 16 + q4 * 4 + r;
        const float v = acc[i][j][r] + b;
        if (F32OUT)
          ((float*)Cp)[(size_t)row * N + col] = v;
        else
          ((bf16_t*)Cp)[(size_t)row * N + col] = (bf16_t)v;
      }
    }
}

// ---------------------------------------------------------------------------
// Fused QKV-projection + windowed attention. One 256-thread block per
// (window, head). Phase 1: qkv[128,192] = x_win[128,1024] @ Wpk_h^T, m97-style
// staging (Xs 8K + Ws 12K). Epilogue scatters acc into LDS: q (scaled by
// 1/8, row-major [128][72]), k (row-major [128][72]), V TRANSPOSED
// ([64 dims][136 tokens] -> both PV operands read as ds_read_b128).
// Phase 2: S=q k^T, softmax (16-lane xor-reduce), P -> LDS (aliases q+k),
// O = P V, store o slice [128,64] merged-head.
// LDS 54272 B total -> 2 blocks/CU.
__global__ __launch_bounds__(256, 2) void qkv_attn(
    const bf16_t* __restrict__ X,    // [16384,1024]
    const bf16_t* __restrict__ Wpk,  // [16][192][1024]
    const float* __restrict__ bin,   // [3072]
    bf16_t* __restrict__ o)          // [16384,1024] merged heads
{
  __shared__ bf16_t smem[27136];     // 54272 B
  bf16_t* Xs  = smem;                // [128*32] staging (phase 1 only)
  bf16_t* Ws  = smem + 4096;         // [192*32] staging
  bf16_t* qs  = smem;                // [128][72] (aliases staging, post-barrier)
  bf16_t* ks  = smem + 9216;         // [128][72]
  bf16_t* vsT = smem + 18432;        // [64][136] V transposed
  bf16_t* Ps  = smem;                // [128][136] (aliases qs+ks, post-barrier)

  const int h    = blockIdx.x;       // head 0..15
  const int wid  = blockIdx.y;       // window 0..127
  const int tid  = threadIdx.x;
  const int lane = tid & 63;
  const int wave = tid >> 6;
  const int n16  = lane & 15;
  const int q4   = lane >> 4;
  const int wm   = (wave >> 1) * 64;   // wave M-offset (0/64)
  const int wn   = (wave & 1) * 96;    // wave N-offset (0/96)

  const bf16_t* Xg = X + (size_t)wid * 128 * 1024;
  const bf16_t* Wg = Wpk + (size_t)h * 192 * 1024;

  // ---- phase 1: qkv = x @ W^T   (M=128, N=192, K=1024)
  floatx4 acc[4][6] = {};
  for (int k0 = 0; k0 < 1024; k0 += 32) {
    __syncthreads();
#pragma unroll
    for (int it = 0; it < 2; ++it) {  // X: 512 chunks of 8
      const int ch = it * 256 + wave * 64 + lane;
      gld_lds16(Xg + (size_t)(ch >> 2) * 1024 + k0 + (ch & 3) * 8,
                Xs + (it * 256 + wave * 64) * 8);
    }
#pragma unroll
    for (int it = 0; it < 3; ++it) {  // W: 768 chunks of 8
      const int ch = it * 256 + wave * 64 + lane;
      gld_lds16(Wg + (size_t)(ch >> 2) * 1024 + k0 + (ch & 3) * 8,
                Ws + (it * 256 + wave * 64) * 8);
    }
    __syncthreads();

    bf16x8 af[4], bfr[6];
#pragma unroll
    for (int i = 0; i < 4; ++i)
      af[i] = *(const bf16x8*)&Xs[(wm + i * 16 + n16) * 32 + q4 * 8];
#pragma unroll
    for (int j = 0; j < 6; ++j)
      bfr[j] = *(const bf16x8*)&Ws[(wn + j * 16 + n16) * 32 + q4 * 8];
#pragma unroll
    for (int i = 0; i < 4; ++i)
#pragma unroll
      for (int j = 0; j < 6; ++j)
        acc[i][j] = MFMA_16x16x32(af[i], bfr[j], acc[i][j]);
  }
  __syncthreads();  // staging region dead -> qs may alias it

  // ---- epilogue: scatter acc -> qs (scaled), ks, vsT
#pragma unroll
  for (int j = 0; j < 6; ++j) {
    const int base = wn + j * 16;   // wave-uniform
    const int col  = base + n16;    // 0..191
    const int gb = (base < 64) ? h * 64 + col
                 : (base < 128) ? 1024 + h * 64 + (col - 64)
                                : 2048 + h * 64 + (col - 128);
    const float bias = bin[gb];
#pragma unroll
    for (int i = 0; i < 4; ++i) {
      const int row0 = wm + i * 16 + q4 * 4;
      if (base < 64) {        // q, fold softmax scale 1/sqrt(64)
#pragma unroll
        for (int r = 0; r < 4; ++r)
          qs[(row0 + r) * 72 + col] = (bf16_t)((acc[i][j][r] + bias) * 0.125f);
      } else if (base < 128) {  // k
#pragma unroll
        for (int r = 0; r < 4; ++r)
          ks[(row0 + r) * 72 + (col - 64)] = (bf16_t)(acc[i][j][r] + bias);
      } else {                  // v -> transposed, 4 consecutive tokens = b64
        bf16x4 pv;
#pragma unroll
        for (int r = 0; r < 4; ++r) pv[r] = (bf16_t)(acc[i][j][r] + bias);
        *(bf16x4*)&vsT[(col - 128) * 136 + row0] = pv;
      }
    }
  }
  __syncthreads();

  // ---- S = q k^T  (wave w owns S rows [32w, 32w+32), K=64)
  floatx4 sacc[2][8] = {};
#pragma unroll
  for (int ks0 = 0; ks0 < 2; ++ks0) {
    bf16x8 aq[2];
#pragma unroll
    for (int i = 0; i < 2; ++i)
      aq[i] = *(const bf16x8*)&qs[(wave * 32 + i * 16 + n16) * 72 + ks0 * 32 + q4 * 8];
#pragma unroll
    for (int j = 0; j < 8; ++j) {
      bf16x8 bk = *(const bf16x8*)&ks[(j * 16 + n16) * 72 + ks0 * 32 + q4 * 8];
      sacc[0][j] = MFMA_16x16x32(aq[0], bk, sacc[0][j]);
      sacc[1][j] = MFMA_16x16x32(aq[1], bk, sacc[1][j]);
    }
  }
  __syncthreads();  // q/k reads done; Ps may overwrite their LDS

  // ---- softmax (scale already folded into q)
#pragma unroll
  for (int i = 0; i < 2; ++i) {
#pragma unroll
    for (int r = 0; r < 4; ++r) {
      float vals[8];
      float mx = -1e30f;
#pragma unroll
      for (int j = 0; j < 8; ++j) {
        vals[j] = sacc[i][j][r];
        mx = fmaxf(mx, vals[j]);
      }
      for (int m = 1; m < 16; m <<= 1) mx = fmaxf(mx, __shfl_xor(mx, m, 64));
      float s = 0.f;
#pragma unroll
      for (int j = 0; j < 8; ++j) {
        vals[j] = __expf(vals[j] - mx);
        s += vals[j];
      }
      for (int m = 1; m < 16; m <<= 1) s += __shfl_xor(s, m, 64);
      const float inv = 1.0f / s;
      const int prow = wave * 32 + i * 16 + q4 * 4 + r;
#pragma unroll
      for (int j = 0; j < 8; ++j)
        Ps[prow * 136 + j * 16 + n16] = (bf16_t)(vals[j] * inv);
    }
  }
  __syncthreads();

  // ---- O = P V  (K=128; both operands via ds_read_b128)
  floatx4 oacc[2][4] = {};
#pragma unroll
  for (int kk = 0; kk < 4; ++kk) {
    bf16x8 ap[2];
#pragma unroll
    for (int i = 0; i < 2; ++i)
      ap[i] = *(const bf16x8*)&Ps[(wave * 32 + i * 16 + n16) * 136 + kk * 32 + q4 * 8];
#pragma unroll
    for (int j = 0; j < 4; ++j) {
      bf16x8 bv = *(const bf16x8*)&vsT[(j * 16 + n16) * 136 + kk * 32 + q4 * 8];
      oacc[0][j] = MFMA_16x16x32(ap[0], bv, oacc[0][j]);
      oacc[1][j] = MFMA_16x16x32(ap[1], bv, oacc[1][j]);
    }
  }

  // ---- write o slice, merged-head layout [token][h*64+d]
  bf16_t* go = o + (size_t)wid * 128 * 1024 + h * 64;
#pragma unroll
  for (int i = 0; i < 2; ++i)
#pragma unroll
    for (int j = 0; j < 4; ++j)
#pragma unroll
      for (int r = 0; r < 4; ++r) {
        const int row = wave * 32 + i * 16 + q4 * 4 + r;
        go[(size_t)row * 1024 + j * 16 + n16] = (bf16_t)oacc[i][j][r];
      }
}

// ---------------------------------------------------------------------------
extern "C" void kernel_launch(void* const* d_in, const int* in_sizes, int n_in,
                              void* d_out, int out_size, void* d_ws, size_t ws_size,
                              hipStream_t stream) {
  const float* x    = (const float*)d_in[0];
  const float* Win  = (const float*)d_in[1];   // [3072,1024]
  const float* bin  = (const float*)d_in[2];   // [3072]
  const float* Wout = (const float*)d_in[3];   // [1024,1024]
  const float* bout = (const float*)d_in[4];   // [1024]
  float* out = (float*)d_out;

  const size_t M = 16384, H = 1024, H3 = 3072;

  // workspace layout (~72 MB): xb | Wpk | Woutb | ob
  bf16_t* xb    = (bf16_t*)d_ws;        // M*H
  bf16_t* Wpk   = xb + M * H;           // H3*H (head-packed)
  bf16_t* Woutb = Wpk + H3 * H;         // H*H
  bf16_t* ob    = Woutb + H * H;        // M*H

  cvt_f32_to_bf16<<<dim3((unsigned)(M * H / 8 / 256)), 256, 0, stream>>>(
      x, xb, (int)(M * H / 8));
  cvt_repack_win<<<dim3((unsigned)H3), 128, 0, stream>>>(Win, Wpk);
  cvt_f32_to_bf16<<<dim3((unsigned)(H * H / 8 / 256)), 256, 0, stream>>>(
      Wout, Woutb, (int)(H * H / 8));

  qkv_attn<<<dim3(16, 128), 256, 0, stream>>>(xb, Wpk, bin, ob);

  gemm_bt<true><<<dim3((unsigned)(H / 128), (unsigned)(M / 128)), 256, 0, stream>>>(
      ob, Woutb, bout, out, (int)M, (int)H, (int)H);
}

// Round 3
// 308.604 us; speedup vs baseline: 1.1165x; 1.0814x over previous
//
#include <hip/hip_runtime.h>
#include <hip/hip_bf16.h>
#include <cstdint>

// ---------------------------------------------------------------------------
// LocalWindowTransformer: windowed MHA, B=4 L=4096 H=1024 NH=16 hd=64 P=128
// R3: qkv_attn occupancy 2->3 blocks/CU (LDS 54272->53248 via XOR-swizzled
//     vsT), softmax diet (no max-sub, deferred 1/sum into O), XCD-affine grid.
// MFMA 16x16x32 bf16 layouts (HW-verified per guide):
//   A-frag: lane holds A[m=lane&15][k=(lane>>4)*8+j], j=0..7
//   B-frag: lane holds B_hw[k=(lane>>4)*8+j][n=lane&15]
//   C/D   : reg r holds C[row=(lane>>4)*4+r][col=lane&15]
// ---------------------------------------------------------------------------

typedef __bf16 bf16_t;
typedef __bf16 bf16x8 __attribute__((ext_vector_type(8)));
typedef __bf16 bf16x4 __attribute__((ext_vector_type(4)));
typedef float  floatx4 __attribute__((ext_vector_type(4)));

#define MFMA_16x16x32(A, B, C) __builtin_amdgcn_mfma_f32_16x16x32_bf16(A, B, C, 0, 0, 0)

// async global->LDS, 16B per lane; LDS dest = wave-uniform base + lane*16
__device__ __forceinline__ void gld_lds16(const bf16_t* g, bf16_t* l) {
  __builtin_amdgcn_global_load_lds(
      (__attribute__((address_space(1))) void*)(void*)(g),
      (__attribute__((address_space(3))) void*)(l), 16, 0, 0);
}

// ---------------------------------------------------------------------------
__global__ void cvt_f32_to_bf16(const float* __restrict__ src,
                                bf16_t* __restrict__ dst, int n8) {
  int i = blockIdx.x * blockDim.x + threadIdx.x;
  if (i >= n8) return;
  const float4* s4 = (const float4*)src;
  float4 a = s4[2 * (size_t)i];
  float4 b = s4[2 * (size_t)i + 1];
  bf16x8 o;
  o[0] = (bf16_t)a.x; o[1] = (bf16_t)a.y; o[2] = (bf16_t)a.z; o[3] = (bf16_t)a.w;
  o[4] = (bf16_t)b.x; o[5] = (bf16_t)b.y; o[6] = (bf16_t)b.z; o[7] = (bf16_t)b.w;
  *(bf16x8*)(dst + (size_t)i * 8) = o;
}

// Repack Win [3072,1024] f32 -> Wpk [16 heads][192 rows][1024] bf16,
// rows per head: q(h*64..), k(1024+h*64..), v(2048+h*64..)
__global__ void cvt_repack_win(const float* __restrict__ Win,
                               bf16_t* __restrict__ Wpk) {
  const int dr = blockIdx.x;              // packed row 0..3071
  const int head = dr / 192, s = dr - head * 192;
  const int src = (s < 64) ? head * 64 + s
                : (s < 128) ? 1024 + head * 64 + (s - 64)
                            : 2048 + head * 64 + (s - 128);
  const float4* srow = (const float4*)(Win + (size_t)src * 1024);
  const int i = threadIdx.x;              // 128 threads x 8 elems
  float4 a = srow[2 * i];
  float4 b = srow[2 * i + 1];
  bf16x8 o;
  o[0] = (bf16_t)a.x; o[1] = (bf16_t)a.y; o[2] = (bf16_t)a.z; o[3] = (bf16_t)a.w;
  o[4] = (bf16_t)b.x; o[5] = (bf16_t)b.y; o[6] = (bf16_t)b.z; o[7] = (bf16_t)b.w;
  *(bf16x8*)(Wpk + (size_t)dr * 1024 + i * 8) = o;
}

// ---------------------------------------------------------------------------
// m97-style GEMM (used for the out-projection): BM=BN=128, BK=32, 256 thr.
template <bool F32OUT>
__global__ __launch_bounds__(256, 2) void gemm_bt(
    const bf16_t* __restrict__ A, const bf16_t* __restrict__ Bm,
    const float* __restrict__ bias, void* __restrict__ Cp,
    int M, int N, int K) {
  __shared__ bf16_t As[128 * 32];
  __shared__ bf16_t Bs[128 * 32];
  const int tid  = threadIdx.x;
  const int lane = tid & 63;
  const int wave = tid >> 6;
  const int n16  = lane & 15;
  const int q4   = lane >> 4;
  const int wm   = (wave >> 1) * 64;
  const int wn   = (wave & 1) * 64;
  const int m0   = blockIdx.y * 128;
  const int n0   = blockIdx.x * 128;

  floatx4 acc[4][4] = {};

  for (int k0 = 0; k0 < K; k0 += 32) {
    __syncthreads();
#pragma unroll
    for (int it = 0; it < 2; ++it) {
      const int ch = it * 256 + wave * 64 + lane;  // 512 chunks of 8 bf16
      const int r = ch >> 2, c = (ch & 3) * 8;
      gld_lds16(A + (size_t)(m0 + r) * K + k0 + c,
                As + (size_t)(it * 256 + wave * 64) * 8);
      gld_lds16(Bm + (size_t)(n0 + r) * K + k0 + c,
                Bs + (size_t)(it * 256 + wave * 64) * 8);
    }
    __syncthreads();

    bf16x8 af[4], bfr[4];
#pragma unroll
    for (int i = 0; i < 4; ++i)
      af[i] = *(const bf16x8*)&As[(wm + i * 16 + n16) * 32 + q4 * 8];
#pragma unroll
    for (int j = 0; j < 4; ++j)
      bfr[j] = *(const bf16x8*)&Bs[(wn + j * 16 + n16) * 32 + q4 * 8];
#pragma unroll
    for (int i = 0; i < 4; ++i)
#pragma unroll
      for (int j = 0; j < 4; ++j)
        acc[i][j] = MFMA_16x16x32(af[i], bfr[j], acc[i][j]);
  }

#pragma unroll
  for (int i = 0; i < 4; ++i)
#pragma unroll
    for (int j = 0; j < 4; ++j) {
      const int col = n0 + wn + j * 16 + n16;
      const float b = bias[col];
#pragma unroll
      for (int r = 0; r < 4; ++r) {
        const int row = m0 + wm + i * 16 + q4 * 4 + r;
        const float v = acc[i][j][r] + b;
        if (F32OUT)
          ((float*)Cp)[(size_t)row * N + col] = v;
        else
          ((bf16_t*)Cp)[(size_t)row * N + col] = (bf16_t)v;
      }
    }
}

// ---------------------------------------------------------------------------
// Fused QKV-projection + windowed attention. One 256-thread block per
// (window, head). Phase 1: qkv[128,192] = x_win[128,1024] @ Wpk_h^T, m97-style
// staging (Xs 8K + Ws 12K B). Epilogue scatters acc into LDS: q (scaled 1/8,
// [128][72]), k ([128][72]), V transposed into XOR-swizzled [64][128]
// (token-chunk-of-8 ^ n16 -> bank-balanced b64 writes AND b128 PV reads).
// Phase 2: S=q k^T; softmax with NO max-sub (logits bounded ~|4|), P stored
// unnormalized, 1/sum folded into O at the end (S and O share C-layout rows).
// LDS 53248 B -> 3 blocks/CU (the R2->R3 occupancy lever).
__global__ __launch_bounds__(256, 3) void qkv_attn(
    const bf16_t* __restrict__ X,    // [16384,1024]
    const bf16_t* __restrict__ Wpk,  // [16][192][1024]
    const float* __restrict__ bin,   // [3072]
    bf16_t* __restrict__ o)          // [16384,1024] merged heads
{
  __shared__ bf16_t smem[26624];     // 53248 B
  bf16_t* Xs  = smem;                // [128*32] staging (phase 1 only)
  bf16_t* Ws  = smem + 4096;         // [192*32] staging
  bf16_t* qs  = smem;                // [128][72] (aliases staging, post-barrier)
  bf16_t* ks  = smem + 9216;         // [128][72]
  bf16_t* vsT = smem + 18432;        // [64][128] XOR-swizzled
  bf16_t* Ps  = smem;                // [128][136] = 17408 <= 18432 (qs+ks)

  const int wid  = blockIdx.x;       // window 0..127 (XCD-affine: wid%8)
  const int h    = blockIdx.y;       // head 0..15
  const int tid  = threadIdx.x;
  const int lane = tid & 63;
  const int wave = tid >> 6;
  const int n16  = lane & 15;
  const int q4   = lane >> 4;
  const int wm   = (wave >> 1) * 64;   // wave M-offset (0/64)
  const int wn   = (wave & 1) * 96;    // wave N-offset (0/96)

  const bf16_t* Xg = X + (size_t)wid * 128 * 1024;
  const bf16_t* Wg = Wpk + (size_t)h * 192 * 1024;

  // ---- phase 1: qkv = x @ W^T   (M=128, N=192, K=1024)
  floatx4 acc[4][6] = {};
  for (int k0 = 0; k0 < 1024; k0 += 32) {
    __syncthreads();
#pragma unroll
    for (int it = 0; it < 2; ++it) {  // X: 512 chunks of 8
      const int ch = it * 256 + wave * 64 + lane;
      gld_lds16(Xg + (size_t)(ch >> 2) * 1024 + k0 + (ch & 3) * 8,
                Xs + (it * 256 + wave * 64) * 8);
    }
#pragma unroll
    for (int it = 0; it < 3; ++it) {  // W: 768 chunks of 8
      const int ch = it * 256 + wave * 64 + lane;
      gld_lds16(Wg + (size_t)(ch >> 2) * 1024 + k0 + (ch & 3) * 8,
                Ws + (it * 256 + wave * 64) * 8);
    }
    __syncthreads();

    bf16x8 af[4], bfr[6];
#pragma unroll
    for (int i = 0; i < 4; ++i)
      af[i] = *(const bf16x8*)&Xs[(wm + i * 16 + n16) * 32 + q4 * 8];
#pragma unroll
    for (int j = 0; j < 6; ++j)
      bfr[j] = *(const bf16x8*)&Ws[(wn + j * 16 + n16) * 32 + q4 * 8];
#pragma unroll
    for (int i = 0; i < 4; ++i)
#pragma unroll
      for (int j = 0; j < 6; ++j)
        acc[i][j] = MFMA_16x16x32(af[i], bfr[j], acc[i][j]);
  }
  __syncthreads();  // staging region dead -> qs may alias it

  // ---- epilogue: scatter acc -> qs (scaled), ks, vsT (swizzled transpose)
#pragma unroll
  for (int j = 0; j < 6; ++j) {
    const int base = wn + j * 16;   // wave-uniform
    const int col  = base + n16;    // 0..191
    const int gb = (base < 64) ? h * 64 + col
                 : (base < 128) ? 1024 + h * 64 + (col - 64)
                                : 2048 + h * 64 + (col - 128);
    const float bias = bin[gb];
#pragma unroll
    for (int i = 0; i < 4; ++i) {
      const int row0 = wm + i * 16 + q4 * 4;
      if (base < 64) {        // q, fold softmax scale 1/sqrt(64)
#pragma unroll
        for (int r = 0; r < 4; ++r)
          qs[(row0 + r) * 72 + col] = (bf16_t)((acc[i][j][r] + bias) * 0.125f);
      } else if (base < 128) {  // k
#pragma unroll
        for (int r = 0; r < 4; ++r)
          ks[(row0 + r) * 72 + (col - 64)] = (bf16_t)(acc[i][j][r] + bias);
      } else {                  // v -> transposed [dim][token], swizzled
        bf16x4 pv;
#pragma unroll
        for (int r = 0; r < 4; ++r) pv[r] = (bf16_t)(acc[i][j][r] + bias);
        const int d = col - 128;          // dim 0..63; d&15 == n16
        const int c8 = row0 >> 3, pos = row0 & 7;
        *(bf16x4*)&vsT[d * 128 + ((c8 ^ n16) << 3) + pos] = pv;
      }
    }
  }
  __syncthreads();

  // ---- S = q k^T  (wave w owns S rows [32w, 32w+32), K=64)
  floatx4 sacc[2][8] = {};
#pragma unroll
  for (int ks0 = 0; ks0 < 2; ++ks0) {
    bf16x8 aq[2];
#pragma unroll
    for (int i = 0; i < 2; ++i)
      aq[i] = *(const bf16x8*)&qs[(wave * 32 + i * 16 + n16) * 72 + ks0 * 32 + q4 * 8];
#pragma unroll
    for (int j = 0; j < 8; ++j) {
      bf16x8 bk = *(const bf16x8*)&ks[(j * 16 + n16) * 72 + ks0 * 32 + q4 * 8];
      sacc[0][j] = MFMA_16x16x32(aq[0], bk, sacc[0][j]);
      sacc[1][j] = MFMA_16x16x32(aq[1], bk, sacc[1][j]);
    }
  }
  __syncthreads();  // q/k reads done; Ps may overwrite their LDS

  // ---- softmax: no max-sub (logits bounded), P unnormalized, defer 1/sum
  float invs[2][4];
#pragma unroll
  for (int i = 0; i < 2; ++i) {
#pragma unroll
    for (int r = 0; r < 4; ++r) {
      float vals[8];
      float s = 0.f;
#pragma unroll
      for (int j = 0; j < 8; ++j) {
        vals[j] = __expf(sacc[i][j][r]);
        s += vals[j];
      }
      for (int m = 1; m < 16; m <<= 1) s += __shfl_xor(s, m, 64);
      invs[i][r] = 1.0f / s;
      const int prow = wave * 32 + i * 16 + q4 * 4 + r;
#pragma unroll
      for (int j = 0; j < 8; ++j)
        Ps[prow * 136 + j * 16 + n16] = (bf16_t)vals[j];
    }
  }
  __syncthreads();

  // ---- O = P V  (K=128; both operands via ds_read_b128)
  floatx4 oacc[2][4] = {};
#pragma unroll
  for (int kk = 0; kk < 4; ++kk) {
    bf16x8 ap[2];
#pragma unroll
    for (int i = 0; i < 2; ++i)
      ap[i] = *(const bf16x8*)&Ps[(wave * 32 + i * 16 + n16) * 136 + kk * 32 + q4 * 8];
#pragma unroll
    for (int j = 0; j < 4; ++j) {
      const int d = j * 16 + n16;
      bf16x8 bv = *(const bf16x8*)&vsT[d * 128 + (((kk * 4 + q4) ^ n16) << 3)];
      oacc[0][j] = MFMA_16x16x32(ap[0], bv, oacc[0][j]);
      oacc[1][j] = MFMA_16x16x32(ap[1], bv, oacc[1][j]);
    }
  }

  // ---- write o slice (scaled by 1/rowsum), merged-head layout [tok][h*64+d]
  bf16_t* go = o + (size_t)wid * 128 * 1024 + h * 64;
#pragma unroll
  for (int i = 0; i < 2; ++i)
#pragma unroll
    for (int j = 0; j < 4; ++j)
#pragma unroll
      for (int r = 0; r < 4; ++r) {
        const int row = wave * 32 + i * 16 + q4 * 4 + r;
        go[(size_t)row * 1024 + j * 16 + n16] = (bf16_t)(oacc[i][j][r] * invs[i][r]);
      }
}

// ---------------------------------------------------------------------------
extern "C" void kernel_launch(void* const* d_in, const int* in_sizes, int n_in,
                              void* d_out, int out_size, void* d_ws, size_t ws_size,
                              hipStream_t stream) {
  const float* x    = (const float*)d_in[0];
  const float* Win  = (const float*)d_in[1];   // [3072,1024]
  const float* bin  = (const float*)d_in[2];   // [3072]
  const float* Wout = (const float*)d_in[3];   // [1024,1024]
  const float* bout = (const float*)d_in[4];   // [1024]
  float* out = (float*)d_out;

  const size_t M = 16384, H = 1024, H3 = 3072;

  // workspace layout (~72 MB): xb | Wpk | Woutb | ob
  bf16_t* xb    = (bf16_t*)d_ws;        // M*H
  bf16_t* Wpk   = xb + M * H;           // H3*H (head-packed)
  bf16_t* Woutb = Wpk + H3 * H;         // H*H
  bf16_t* ob    = Woutb + H * H;        // M*H

  cvt_f32_to_bf16<<<dim3((unsigned)(M * H / 8 / 256)), 256, 0, stream>>>(
      x, xb, (int)(M * H / 8));
  cvt_repack_win<<<dim3((unsigned)H3), 128, 0, stream>>>(Win, Wpk);
  cvt_f32_to_bf16<<<dim3((unsigned)(H * H / 8 / 256)), 256, 0, stream>>>(
      Wout, Woutb, (int)(H * H / 8));

  // grid: window-major -> linear id = wid + 128*h -> window pins to XCD wid%8,
  // all 16 heads of a window share that XCD's L2 copy of X.
  qkv_attn<<<dim3(128, 16), 256, 0, stream>>>(xb, Wpk, bin, ob);

  gemm_bt<true><<<dim3((unsigned)(H / 128), (unsigned)(M / 128)), 256, 0, stream>>>(
      ob, Woutb, bout, out, (int)M, (int)H, (int)H);
}

// Round 4
// 291.334 us; speedup vs baseline: 1.1826x; 1.0593x over previous
//
#include <hip/hip_runtime.h>
#include <hip/hip_bf16.h>
#include <cstdint>

// ---------------------------------------------------------------------------
// LocalWindowTransformer: windowed MHA, B=4 L=4096 H=1024 NH=16 hd=64 P=128
// R4: BK=64 (half the barriers, 48 MFMA/barrier-pair) + source-side XOR
//     swizzle of the 16B staging chunks (c8 ^= row&7) -> conflict-free
//     fragment ds_read_b128 despite global_load_lds's forced-linear dest.
//     Applied to both qkv_attn phase 1 and gemm_bt.
// MFMA 16x16x32 bf16 layouts (HW-verified per guide):
//   A-frag: lane holds A[m=lane&15][k=(lane>>4)*8+j], j=0..7
//   B-frag: lane holds B_hw[k=(lane>>4)*8+j][n=lane&15]
//   C/D   : reg r holds C[row=(lane>>4)*4+r][col=lane&15]
// Swizzled staging layout: LDS row r (64 elems) holds chunk kc at elem
//   offset ((kc ^ (r&7))*8); fragment read addr = r*64 + ((kc^(r&7))*8),
//   kc = half*4 + q4. 16 lanes (rows) -> 8 distinct bank-quads, 2-way = free.
// ---------------------------------------------------------------------------

typedef __bf16 bf16_t;
typedef __bf16 bf16x8 __attribute__((ext_vector_type(8)));
typedef __bf16 bf16x4 __attribute__((ext_vector_type(4)));
typedef float  floatx4 __attribute__((ext_vector_type(4)));

#define MFMA_16x16x32(A, B, C) __builtin_amdgcn_mfma_f32_16x16x32_bf16(A, B, C, 0, 0, 0)

// async global->LDS, 16B per lane; LDS dest = wave-uniform base + lane*16
__device__ __forceinline__ void gld_lds16(const bf16_t* g, bf16_t* l) {
  __builtin_amdgcn_global_load_lds(
      (__attribute__((address_space(1))) void*)(void*)(g),
      (__attribute__((address_space(3))) void*)(l), 16, 0, 0);
}

// ---------------------------------------------------------------------------
__global__ void cvt_f32_to_bf16(const float* __restrict__ src,
                                bf16_t* __restrict__ dst, int n8) {
  int i = blockIdx.x * blockDim.x + threadIdx.x;
  if (i >= n8) return;
  const float4* s4 = (const float4*)src;
  float4 a = s4[2 * (size_t)i];
  float4 b = s4[2 * (size_t)i + 1];
  bf16x8 o;
  o[0] = (bf16_t)a.x; o[1] = (bf16_t)a.y; o[2] = (bf16_t)a.z; o[3] = (bf16_t)a.w;
  o[4] = (bf16_t)b.x; o[5] = (bf16_t)b.y; o[6] = (bf16_t)b.z; o[7] = (bf16_t)b.w;
  *(bf16x8*)(dst + (size_t)i * 8) = o;
}

// Repack Win [3072,1024] f32 -> Wpk [16 heads][192 rows][1024] bf16,
// rows per head: q(h*64..), k(1024+h*64..), v(2048+h*64..)
__global__ void cvt_repack_win(const float* __restrict__ Win,
                               bf16_t* __restrict__ Wpk) {
  const int dr = blockIdx.x;              // packed row 0..3071
  const int head = dr / 192, s = dr - head * 192;
  const int src = (s < 64) ? head * 64 + s
                : (s < 128) ? 1024 + head * 64 + (s - 64)
                            : 2048 + head * 64 + (s - 128);
  const float4* srow = (const float4*)(Win + (size_t)src * 1024);
  const int i = threadIdx.x;              // 128 threads x 8 elems
  float4 a = srow[2 * i];
  float4 b = srow[2 * i + 1];
  bf16x8 o;
  o[0] = (bf16_t)a.x; o[1] = (bf16_t)a.y; o[2] = (bf16_t)a.z; o[3] = (bf16_t)a.w;
  o[4] = (bf16_t)b.x; o[5] = (bf16_t)b.y; o[6] = (bf16_t)b.z; o[7] = (bf16_t)b.w;
  *(bf16x8*)(Wpk + (size_t)dr * 1024 + i * 8) = o;
}

// ---------------------------------------------------------------------------
// Out-projection GEMM: BM=BN=128, BK=64, swizzled staging, 256 threads.
template <bool F32OUT>
__global__ __launch_bounds__(256, 3) void gemm_bt(
    const bf16_t* __restrict__ A, const bf16_t* __restrict__ Bm,
    const float* __restrict__ bias, void* __restrict__ Cp,
    int M, int N, int K) {
  __shared__ bf16_t As[128 * 64];
  __shared__ bf16_t Bs[128 * 64];
  const int tid  = threadIdx.x;
  const int lane = tid & 63;
  const int wave = tid >> 6;
  const int n16  = lane & 15;
  const int q4   = lane >> 4;
  const int wm   = (wave >> 1) * 64;
  const int wn   = (wave & 1) * 64;
  const int m0   = blockIdx.y * 128;
  const int n0   = blockIdx.x * 128;

  floatx4 acc[4][4] = {};

  for (int k0 = 0; k0 < K; k0 += 64) {
    __syncthreads();
#pragma unroll
    for (int it = 0; it < 4; ++it) {
      const int ch = it * 256 + tid;         // 1024 chunks of 8 per matrix
      const int r  = ch >> 3;
      const int c8 = (ch & 7) ^ (r & 7);     // source-side XOR swizzle
      gld_lds16(A  + (size_t)(m0 + r) * K + k0 + c8 * 8,
                As + (it * 256 + wave * 64) * 8);
      gld_lds16(Bm + (size_t)(n0 + r) * K + k0 + c8 * 8,
                Bs + (it * 256 + wave * 64) * 8);
    }
    __syncthreads();

#pragma unroll
    for (int half = 0; half < 2; ++half) {
      bf16x8 af[4], bfr[4];
#pragma unroll
      for (int i = 0; i < 4; ++i) {
        const int row = wm + i * 16 + n16;
        af[i] = *(const bf16x8*)&As[row * 64 + (((half * 4 + q4) ^ (row & 7)) * 8)];
      }
#pragma unroll
      for (int j = 0; j < 4; ++j) {
        const int row = wn + j * 16 + n16;
        bfr[j] = *(const bf16x8*)&Bs[row * 64 + (((half * 4 + q4) ^ (row & 7)) * 8)];
      }
#pragma unroll
      for (int i = 0; i < 4; ++i)
#pragma unroll
        for (int j = 0; j < 4; ++j)
          acc[i][j] = MFMA_16x16x32(af[i], bfr[j], acc[i][j]);
    }
  }

#pragma unroll
  for (int i = 0; i < 4; ++i)
#pragma unroll
    for (int j = 0; j < 4; ++j) {
      const int col = n0 + wn + j * 16 + n16;
      const float b = bias[col];
#pragma unroll
      for (int r = 0; r < 4; ++r) {
        const int row = m0 + wm + i * 16 + q4 * 4 + r;
        const float v = acc[i][j][r] + b;
        if (F32OUT)
          ((float*)Cp)[(size_t)row * N + col] = v;
        else
          ((bf16_t*)Cp)[(size_t)row * N + col] = (bf16_t)v;
      }
    }
}

// ---------------------------------------------------------------------------
// Fused QKV-projection + windowed attention. One 256-thread block per
// (window, head). Phase 1: qkv[128,192] = x_win[128,1024] @ Wpk_h^T, BK=64
// swizzled staging (Xs 16K + Ws 24K B, aliased onto attention regions).
// Epilogue scatters acc into LDS: q (scaled 1/8, [128][72]), k ([128][72]),
// V transposed into XOR-swizzled [64][128]. Phase 2: S=q k^T; softmax with
// no max-sub (logits bounded), P unnormalized, 1/sum folded into O.
// LDS 53248 B -> 3 blocks/CU.
__global__ __launch_bounds__(256, 3) void qkv_attn(
    const bf16_t* __restrict__ X,    // [16384,1024]
    const bf16_t* __restrict__ Wpk,  // [16][192][1024]
    const float* __restrict__ bin,   // [3072]
    bf16_t* __restrict__ o)          // [16384,1024] merged heads
{
  __shared__ bf16_t smem[26624];     // 53248 B
  bf16_t* Xs  = smem;                // [128][64] staging (phase 1 only)
  bf16_t* Ws  = smem + 8192;         // [192][64] staging (ends 20480)
  bf16_t* qs  = smem;                // [128][72] (aliases staging, post-barrier)
  bf16_t* ks  = smem + 9216;         // [128][72]
  bf16_t* vsT = smem + 18432;        // [64][128] XOR-swizzled
  bf16_t* Ps  = smem;                // [128][136] = 17408 <= 18432 (qs+ks)

  const int wid  = blockIdx.x;       // window 0..127 (XCD-affine: wid%8)
  const int h    = blockIdx.y;       // head 0..15
  const int tid  = threadIdx.x;
  const int lane = tid & 63;
  const int wave = tid >> 6;
  const int n16  = lane & 15;
  const int q4   = lane >> 4;
  const int wm   = (wave >> 1) * 64;   // wave M-offset (0/64)
  const int wn   = (wave & 1) * 96;    // wave N-offset (0/96)

  const bf16_t* Xg = X + (size_t)wid * 128 * 1024;
  const bf16_t* Wg = Wpk + (size_t)h * 192 * 1024;

  // ---- phase 1: qkv = x @ W^T   (M=128, N=192, K=1024, BK=64)
  floatx4 acc[4][6] = {};
  for (int k0 = 0; k0 < 1024; k0 += 64) {
    __syncthreads();
#pragma unroll
    for (int it = 0; it < 4; ++it) {  // X: 1024 chunks of 8
      const int ch = it * 256 + tid;
      const int r  = ch >> 3;
      const int c8 = (ch & 7) ^ (r & 7);
      gld_lds16(Xg + (size_t)r * 1024 + k0 + c8 * 8,
                Xs + (it * 256 + wave * 64) * 8);
    }
#pragma unroll
    for (int it = 0; it < 6; ++it) {  // W: 1536 chunks of 8
      const int ch = it * 256 + tid;
      const int r  = ch >> 3;
      const int c8 = (ch & 7) ^ (r & 7);
      gld_lds16(Wg + (size_t)r * 1024 + k0 + c8 * 8,
                Ws + (it * 256 + wave * 64) * 8);
    }
    __syncthreads();

#pragma unroll
    for (int half = 0; half < 2; ++half) {
      bf16x8 af[4], bfr[6];
#pragma unroll
      for (int i = 0; i < 4; ++i) {
        const int row = wm + i * 16 + n16;
        af[i] = *(const bf16x8*)&Xs[row * 64 + (((half * 4 + q4) ^ (row & 7)) * 8)];
      }
#pragma unroll
      for (int j = 0; j < 6; ++j) {
        const int row = wn + j * 16 + n16;
        bfr[j] = *(const bf16x8*)&Ws[row * 64 + (((half * 4 + q4) ^ (row & 7)) * 8)];
      }
#pragma unroll
      for (int i = 0; i < 4; ++i)
#pragma unroll
        for (int j = 0; j < 6; ++j)
          acc[i][j] = MFMA_16x16x32(af[i], bfr[j], acc[i][j]);
    }
  }
  __syncthreads();  // staging region dead -> qs/ks/vsT may alias it

  // ---- epilogue: scatter acc -> qs (scaled), ks, vsT (swizzled transpose)
#pragma unroll
  for (int j = 0; j < 6; ++j) {
    const int base = wn + j * 16;   // wave-uniform
    const int col  = base + n16;    // 0..191
    const int gb = (base < 64) ? h * 64 + col
                 : (base < 128) ? 1024 + h * 64 + (col - 64)
                                : 2048 + h * 64 + (col - 128);
    const float bias = bin[gb];
#pragma unroll
    for (int i = 0; i < 4; ++i) {
      const int row0 = wm + i * 16 + q4 * 4;
      if (base < 64) {        // q, fold softmax scale 1/sqrt(64)
#pragma unroll
        for (int r = 0; r < 4; ++r)
          qs[(row0 + r) * 72 + col] = (bf16_t)((acc[i][j][r] + bias) * 0.125f);
      } else if (base < 128) {  // k
#pragma unroll
        for (int r = 0; r < 4; ++r)
          ks[(row0 + r) * 72 + (col - 64)] = (bf16_t)(acc[i][j][r] + bias);
      } else {                  // v -> transposed [dim][token], swizzled
        bf16x4 pv;
#pragma unroll
        for (int r = 0; r < 4; ++r) pv[r] = (bf16_t)(acc[i][j][r] + bias);
        const int d = col - 128;          // dim 0..63; d&15 == n16
        const int c8 = row0 >> 3, pos = row0 & 7;
        *(bf16x4*)&vsT[d * 128 + ((c8 ^ n16) << 3) + pos] = pv;
      }
    }
  }
  __syncthreads();

  // ---- S = q k^T  (wave w owns S rows [32w, 32w+32), K=64)
  floatx4 sacc[2][8] = {};
#pragma unroll
  for (int ks0 = 0; ks0 < 2; ++ks0) {
    bf16x8 aq[2];
#pragma unroll
    for (int i = 0; i < 2; ++i)
      aq[i] = *(const bf16x8*)&qs[(wave * 32 + i * 16 + n16) * 72 + ks0 * 32 + q4 * 8];
#pragma unroll
    for (int j = 0; j < 8; ++j) {
      bf16x8 bk = *(const bf16x8*)&ks[(j * 16 + n16) * 72 + ks0 * 32 + q4 * 8];
      sacc[0][j] = MFMA_16x16x32(aq[0], bk, sacc[0][j]);
      sacc[1][j] = MFMA_16x16x32(aq[1], bk, sacc[1][j]);
    }
  }
  __syncthreads();  // q/k reads done; Ps may overwrite their LDS

  // ---- softmax: no max-sub (logits bounded), P unnormalized, defer 1/sum
  float invs[2][4];
#pragma unroll
  for (int i = 0; i < 2; ++i) {
#pragma unroll
    for (int r = 0; r < 4; ++r) {
      float vals[8];
      float s = 0.f;
#pragma unroll
      for (int j = 0; j < 8; ++j) {
        vals[j] = __expf(sacc[i][j][r]);
        s += vals[j];
      }
      for (int m = 1; m < 16; m <<= 1) s += __shfl_xor(s, m, 64);
      invs[i][r] = 1.0f / s;
      const int prow = wave * 32 + i * 16 + q4 * 4 + r;
#pragma unroll
      for (int j = 0; j < 8; ++j)
        Ps[prow * 136 + j * 16 + n16] = (bf16_t)vals[j];
    }
  }
  __syncthreads();

  // ---- O = P V  (K=128; both operands via ds_read_b128)
  floatx4 oacc[2][4] = {};
#pragma unroll
  for (int kk = 0; kk < 4; ++kk) {
    bf16x8 ap[2];
#pragma unroll
    for (int i = 0; i < 2; ++i)
      ap[i] = *(const bf16x8*)&Ps[(wave * 32 + i * 16 + n16) * 136 + kk * 32 + q4 * 8];
#pragma unroll
    for (int j = 0; j < 4; ++j) {
      const int d = j * 16 + n16;
      bf16x8 bv = *(const bf16x8*)&vsT[d * 128 + (((kk * 4 + q4) ^ n16) << 3)];
      oacc[0][j] = MFMA_16x16x32(ap[0], bv, oacc[0][j]);
      oacc[1][j] = MFMA_16x16x32(ap[1], bv, oacc[1][j]);
    }
  }

  // ---- write o slice (scaled by 1/rowsum), merged-head layout [tok][h*64+d]
  bf16_t* go = o + (size_t)wid * 128 * 1024 + h * 64;
#pragma unroll
  for (int i = 0; i < 2; ++i)
#pragma unroll
    for (int j = 0; j < 4; ++j)
#pragma unroll
      for (int r = 0; r < 4; ++r) {
        const int row = wave * 32 + i * 16 + q4 * 4 + r;
        go[(size_t)row * 1024 + j * 16 + n16] = (bf16_t)(oacc[i][j][r] * invs[i][r]);
      }
}

// ---------------------------------------------------------------------------
extern "C" void kernel_launch(void* const* d_in, const int* in_sizes, int n_in,
                              void* d_out, int out_size, void* d_ws, size_t ws_size,
                              hipStream_t stream) {
  const float* x    = (const float*)d_in[0];
  const float* Win  = (const float*)d_in[1];   // [3072,1024]
  const float* bin  = (const float*)d_in[2];   // [3072]
  const float* Wout = (const float*)d_in[3];   // [1024,1024]
  const float* bout = (const float*)d_in[4];   // [1024]
  float* out = (float*)d_out;

  const size_t M = 16384, H = 1024, H3 = 3072;

  // workspace layout (~72 MB): xb | Wpk | Woutb | ob
  bf16_t* xb    = (bf16_t*)d_ws;        // M*H
  bf16_t* Wpk   = xb + M * H;           // H3*H (head-packed)
  bf16_t* Woutb = Wpk + H3 * H;         // H*H
  bf16_t* ob    = Woutb + H * H;        // M*H

  cvt_f32_to_bf16<<<dim3((unsigned)(M * H / 8 / 256)), 256, 0, stream>>>(
      x, xb, (int)(M * H / 8));
  cvt_repack_win<<<dim3((unsigned)H3), 128, 0, stream>>>(Win, Wpk);
  cvt_f32_to_bf16<<<dim3((unsigned)(H * H / 8 / 256)), 256, 0, stream>>>(
      Wout, Woutb, (int)(H * H / 8));

  // grid: window-major -> linear id = wid + 128*h -> window pins to XCD wid%8,
  // all 16 heads of a window share that XCD's L2 copy of X.
  qkv_attn<<<dim3(128, 16), 256, 0, stream>>>(xb, Wpk, bin, ob);

  // grid.x=8 fast -> XCD = bx -> each XCD keeps one 2MB B-tile L2-resident.
  gemm_bt<true><<<dim3((unsigned)(H / 128), (unsigned)(M / 128)), 256, 0, stream>>>(
      ob, Woutb, bout, out, (int)M, (int)H, (int)H);
}

// Round 5
// 281.654 us; speedup vs baseline: 1.2233x; 1.0344x over previous
//
#include <hip/hip_runtime.h>
#include <hip/hip_bf16.h>
#include <cstdint>

// ---------------------------------------------------------------------------
// LocalWindowTransformer: windowed MHA, B=4 L=4096 H=1024 NH=16 hd=64 P=128
// R5: the hidden bottleneck was the out-projection GEMM (~125us, just under
//     the top-5 cutoff; 273 TF from 2.67 dispatch rounds + low MFMA density).
//     -> gemm_out: BM=128 x BN=256, BK=64, grid(4,128)=512 blocks = exactly
//        one round at 2 blocks/CU, 64 MFMA per wave-iter from 12 ds_reads.
//     -> all three f32->bf16 conversions fused into one dispatch.
//     qkv_attn unchanged from R4 (conflict-free swizzled staging).
// MFMA 16x16x32 bf16 layouts (HW-verified per guide):
//   A-frag: lane holds A[m=lane&15][k=(lane>>4)*8+j], j=0..7
//   B-frag: lane holds B_hw[k=(lane>>4)*8+j][n=lane&15]
//   C/D   : reg r holds C[row=(lane>>4)*4+r][col=lane&15]
// Swizzled staging layout: LDS row r (64 elems) holds chunk kc at elem
//   offset ((kc ^ (r&7))*8); fragment read addr = r*64 + ((kc^(r&7))*8).
// ---------------------------------------------------------------------------

typedef __bf16 bf16_t;
typedef __bf16 bf16x8 __attribute__((ext_vector_type(8)));
typedef __bf16 bf16x4 __attribute__((ext_vector_type(4)));
typedef float  floatx4 __attribute__((ext_vector_type(4)));

#define MFMA_16x16x32(A, B, C) __builtin_amdgcn_mfma_f32_16x16x32_bf16(A, B, C, 0, 0, 0)

// async global->LDS, 16B per lane; LDS dest = wave-uniform base + lane*16
__device__ __forceinline__ void gld_lds16(const bf16_t* g, bf16_t* l) {
  __builtin_amdgcn_global_load_lds(
      (__attribute__((address_space(1))) void*)(void*)(g),
      (__attribute__((address_space(3))) void*)(l), 16, 0, 0);
}

__device__ __forceinline__ void cvt8(const float* __restrict__ s,
                                     bf16_t* __restrict__ d) {
  float4 a = ((const float4*)s)[0];
  float4 b = ((const float4*)s)[1];
  bf16x8 o;
  o[0] = (bf16_t)a.x; o[1] = (bf16_t)a.y; o[2] = (bf16_t)a.z; o[3] = (bf16_t)a.w;
  o[4] = (bf16_t)b.x; o[5] = (bf16_t)b.y; o[6] = (bf16_t)b.z; o[7] = (bf16_t)b.w;
  *(bf16x8*)d = o;
}

// ---------------------------------------------------------------------------
// One fused conversion dispatch, 8-elem chunks:
//   [0, 2097152)              x    [16384,1024] -> xb
//   [2097152, 2228224)        Wout [1024,1024]  -> Woutb
//   [2228224, 2621440)        Win  [3072,1024]  -> Wpk (head-packed repack)
__global__ void cvt_all(const float* __restrict__ x,
                        const float* __restrict__ Win,
                        const float* __restrict__ Wout,
                        bf16_t* __restrict__ xb,
                        bf16_t* __restrict__ Wpk,
                        bf16_t* __restrict__ Woutb) {
  const int idx = blockIdx.x * 256 + threadIdx.x;
  if (idx < 2097152) {
    cvt8(x + (size_t)idx * 8, xb + (size_t)idx * 8);
  } else if (idx < 2228224) {
    const int i = idx - 2097152;
    cvt8(Wout + (size_t)i * 8, Woutb + (size_t)i * 8);
  } else {
    const int c = idx - 2228224;          // 0..393215
    const int dr = c >> 7, i = c & 127;   // packed row, chunk-in-row
    const int head = dr / 192, s = dr - head * 192;
    const int src = (s < 64) ? head * 64 + s
                  : (s < 128) ? 1024 + head * 64 + (s - 64)
                              : 2048 + head * 64 + (s - 128);
    cvt8(Win + (size_t)src * 1024 + i * 8, Wpk + (size_t)dr * 1024 + i * 8);
  }
}

// ---------------------------------------------------------------------------
// Out-projection GEMM: BM=128, BN=256, BK=64, swizzled staging, 256 threads.
// grid(4,128)=512 blocks = exactly 2/CU (one dispatch round, no tail).
// Wave tile 64x128: acc[4][8] (AGPRs). XCD-affine: id%8 pins one B-tile/XCD.
__global__ __launch_bounds__(256, 2) void gemm_out(
    const bf16_t* __restrict__ A, const bf16_t* __restrict__ Bm,
    const float* __restrict__ bias, float* __restrict__ C,
    int M, int N, int K) {
  __shared__ bf16_t As[128 * 64];   // 16 KB
  __shared__ bf16_t Bs[256 * 64];   // 32 KB
  const int tid  = threadIdx.x;
  const int lane = tid & 63;
  const int wave = tid >> 6;
  const int n16  = lane & 15;
  const int q4   = lane >> 4;
  const int wm   = (wave >> 1) * 64;
  const int wn   = (wave & 1) * 128;
  const int m0   = blockIdx.y * 128;
  const int n0   = blockIdx.x * 256;

  floatx4 acc[4][8] = {};

  for (int k0 = 0; k0 < K; k0 += 64) {
    __syncthreads();
#pragma unroll
    for (int it = 0; it < 4; ++it) {       // As: 1024 chunks of 8
      const int ch = it * 256 + tid;
      const int r  = ch >> 3;
      const int c8 = (ch & 7) ^ (r & 7);
      gld_lds16(A + (size_t)(m0 + r) * K + k0 + c8 * 8,
                As + (it * 256 + wave * 64) * 8);
    }
#pragma unroll
    for (int it = 0; it < 8; ++it) {       // Bs: 2048 chunks of 8
      const int ch = it * 256 + tid;
      const int r  = ch >> 3;
      const int c8 = (ch & 7) ^ (r & 7);
      gld_lds16(Bm + (size_t)(n0 + r) * K + k0 + c8 * 8,
                Bs + (it * 256 + wave * 64) * 8);
    }
    __syncthreads();

#pragma unroll
    for (int half = 0; half < 2; ++half) {
      bf16x8 af[4], bfr[8];
#pragma unroll
      for (int i = 0; i < 4; ++i) {
        const int row = wm + i * 16 + n16;
        af[i] = *(const bf16x8*)&As[row * 64 + (((half * 4 + q4) ^ (row & 7)) * 8)];
      }
#pragma unroll
      for (int j = 0; j < 8; ++j) {
        const int row = wn + j * 16 + n16;
        bfr[j] = *(const bf16x8*)&Bs[row * 64 + (((half * 4 + q4) ^ (row & 7)) * 8)];
      }
#pragma unroll
      for (int i = 0; i < 4; ++i)
#pragma unroll
        for (int j = 0; j < 8; ++j)
          acc[i][j] = MFMA_16x16x32(af[i], bfr[j], acc[i][j]);
    }
  }

#pragma unroll
  for (int i = 0; i < 4; ++i)
#pragma unroll
    for (int j = 0; j < 8; ++j) {
      const int col = n0 + wn + j * 16 + n16;
      const float b = bias[col];
#pragma unroll
      for (int r = 0; r < 4; ++r) {
        const int row = m0 + wm + i * 16 + q4 * 4 + r;
        C[(size_t)row * N + col] = acc[i][j][r] + b;
      }
    }
}

// ---------------------------------------------------------------------------
// Fused QKV-projection + windowed attention (unchanged from R4).
// One 256-thread block per (window, head). Phase 1: qkv[128,192] =
// x_win[128,1024] @ Wpk_h^T, BK=64 swizzled staging. Epilogue scatters acc
// into LDS: q (scaled 1/8, [128][72]), k ([128][72]), V transposed into
// XOR-swizzled [64][128]. Phase 2: S=q k^T; softmax with no max-sub (logits
// bounded), P unnormalized, 1/sum folded into O. LDS 53248 B -> 3 blocks/CU.
__global__ __launch_bounds__(256, 3) void qkv_attn(
    const bf16_t* __restrict__ X,    // [16384,1024]
    const bf16_t* __restrict__ Wpk,  // [16][192][1024]
    const float* __restrict__ bin,   // [3072]
    bf16_t* __restrict__ o)          // [16384,1024] merged heads
{
  __shared__ bf16_t smem[26624];     // 53248 B
  bf16_t* Xs  = smem;                // [128][64] staging (phase 1 only)
  bf16_t* Ws  = smem + 8192;         // [192][64] staging (ends 20480)
  bf16_t* qs  = smem;                // [128][72] (aliases staging, post-barrier)
  bf16_t* ks  = smem + 9216;         // [128][72]
  bf16_t* vsT = smem + 18432;        // [64][128] XOR-swizzled
  bf16_t* Ps  = smem;                // [128][136] = 17408 <= 18432 (qs+ks)

  const int wid  = blockIdx.x;       // window 0..127 (XCD-affine: wid%8)
  const int h    = blockIdx.y;       // head 0..15
  const int tid  = threadIdx.x;
  const int lane = tid & 63;
  const int wave = tid >> 6;
  const int n16  = lane & 15;
  const int q4   = lane >> 4;
  const int wm   = (wave >> 1) * 64;   // wave M-offset (0/64)
  const int wn   = (wave & 1) * 96;    // wave N-offset (0/96)

  const bf16_t* Xg = X + (size_t)wid * 128 * 1024;
  const bf16_t* Wg = Wpk + (size_t)h * 192 * 1024;

  // ---- phase 1: qkv = x @ W^T   (M=128, N=192, K=1024, BK=64)
  floatx4 acc[4][6] = {};
  for (int k0 = 0; k0 < 1024; k0 += 64) {
    __syncthreads();
#pragma unroll
    for (int it = 0; it < 4; ++it) {  // X: 1024 chunks of 8
      const int ch = it * 256 + tid;
      const int r  = ch >> 3;
      const int c8 = (ch & 7) ^ (r & 7);
      gld_lds16(Xg + (size_t)r * 1024 + k0 + c8 * 8,
                Xs + (it * 256 + wave * 64) * 8);
    }
#pragma unroll
    for (int it = 0; it < 6; ++it) {  // W: 1536 chunks of 8
      const int ch = it * 256 + tid;
      const int r  = ch >> 3;
      const int c8 = (ch & 7) ^ (r & 7);
      gld_lds16(Wg + (size_t)r * 1024 + k0 + c8 * 8,
                Ws + (it * 256 + wave * 64) * 8);
    }
    __syncthreads();

#pragma unroll
    for (int half = 0; half < 2; ++half) {
      bf16x8 af[4], bfr[6];
#pragma unroll
      for (int i = 0; i < 4; ++i) {
        const int row = wm + i * 16 + n16;
        af[i] = *(const bf16x8*)&Xs[row * 64 + (((half * 4 + q4) ^ (row & 7)) * 8)];
      }
#pragma unroll
      for (int j = 0; j < 6; ++j) {
        const int row = wn + j * 16 + n16;
        bfr[j] = *(const bf16x8*)&Ws[row * 64 + (((half * 4 + q4) ^ (row & 7)) * 8)];
      }
#pragma unroll
      for (int i = 0; i < 4; ++i)
#pragma unroll
        for (int j = 0; j < 6; ++j)
          acc[i][j] = MFMA_16x16x32(af[i], bfr[j], acc[i][j]);
    }
  }
  __syncthreads();  // staging region dead -> qs/ks/vsT may alias it

  // ---- epilogue: scatter acc -> qs (scaled), ks, vsT (swizzled transpose)
#pragma unroll
  for (int j = 0; j < 6; ++j) {
    const int base = wn + j * 16;   // wave-uniform
    const int col  = base + n16;    // 0..191
    const int gb = (base < 64) ? h * 64 + col
                 : (base < 128) ? 1024 + h * 64 + (col - 64)
                                : 2048 + h * 64 + (col - 128);
    const float bias = bin[gb];
#pragma unroll
    for (int i = 0; i < 4; ++i) {
      const int row0 = wm + i * 16 + q4 * 4;
      if (base < 64) {        // q, fold softmax scale 1/sqrt(64)
#pragma unroll
        for (int r = 0; r < 4; ++r)
          qs[(row0 + r) * 72 + col] = (bf16_t)((acc[i][j][r] + bias) * 0.125f);
      } else if (base < 128) {  // k
#pragma unroll
        for (int r = 0; r < 4; ++r)
          ks[(row0 + r) * 72 + (col - 64)] = (bf16_t)(acc[i][j][r] + bias);
      } else {                  // v -> transposed [dim][token], swizzled
        bf16x4 pv;
#pragma unroll
        for (int r = 0; r < 4; ++r) pv[r] = (bf16_t)(acc[i][j][r] + bias);
        const int d = col - 128;          // dim 0..63; d&15 == n16
        const int c8 = row0 >> 3, pos = row0 & 7;
        *(bf16x4*)&vsT[d * 128 + ((c8 ^ n16) << 3) + pos] = pv;
      }
    }
  }
  __syncthreads();

  // ---- S = q k^T  (wave w owns S rows [32w, 32w+32), K=64)
  floatx4 sacc[2][8] = {};
#pragma unroll
  for (int ks0 = 0; ks0 < 2; ++ks0) {
    bf16x8 aq[2];
#pragma unroll
    for (int i = 0; i < 2; ++i)
      aq[i] = *(const bf16x8*)&qs[(wave * 32 + i * 16 + n16) * 72 + ks0 * 32 + q4 * 8];
#pragma unroll
    for (int j = 0; j < 8; ++j) {
      bf16x8 bk = *(const bf16x8*)&ks[(j * 16 + n16) * 72 + ks0 * 32 + q4 * 8];
      sacc[0][j] = MFMA_16x16x32(aq[0], bk, sacc[0][j]);
      sacc[1][j] = MFMA_16x16x32(aq[1], bk, sacc[1][j]);
    }
  }
  __syncthreads();  // q/k reads done; Ps may overwrite their LDS

  // ---- softmax: no max-sub (logits bounded), P unnormalized, defer 1/sum
  float invs[2][4];
#pragma unroll
  for (int i = 0; i < 2; ++i) {
#pragma unroll
    for (int r = 0; r < 4; ++r) {
      float vals[8];
      float s = 0.f;
#pragma unroll
      for (int j = 0; j < 8; ++j) {
        vals[j] = __expf(sacc[i][j][r]);
        s += vals[j];
      }
      for (int m = 1; m < 16; m <<= 1) s += __shfl_xor(s, m, 64);
      invs[i][r] = 1.0f / s;
      const int prow = wave * 32 + i * 16 + q4 * 4 + r;
#pragma unroll
      for (int j = 0; j < 8; ++j)
        Ps[prow * 136 + j * 16 + n16] = (bf16_t)vals[j];
    }
  }
  __syncthreads();

  // ---- O = P V  (K=128; both operands via ds_read_b128)
  floatx4 oacc[2][4] = {};
#pragma unroll
  for (int kk = 0; kk < 4; ++kk) {
    bf16x8 ap[2];
#pragma unroll
    for (int i = 0; i < 2; ++i)
      ap[i] = *(const bf16x8*)&Ps[(wave * 32 + i * 16 + n16) * 136 + kk * 32 + q4 * 8];
#pragma unroll
    for (int j = 0; j < 4; ++j) {
      const int d = j * 16 + n16;
      bf16x8 bv = *(const bf16x8*)&vsT[d * 128 + (((kk * 4 + q4) ^ n16) << 3)];
      oacc[0][j] = MFMA_16x16x32(ap[0], bv, oacc[0][j]);
      oacc[1][j] = MFMA_16x16x32(ap[1], bv, oacc[1][j]);
    }
  }

  // ---- write o slice (scaled by 1/rowsum), merged-head layout [tok][h*64+d]
  bf16_t* go = o + (size_t)wid * 128 * 1024 + h * 64;
#pragma unroll
  for (int i = 0; i < 2; ++i)
#pragma unroll
    for (int j = 0; j < 4; ++j)
#pragma unroll
      for (int r = 0; r < 4; ++r) {
        const int row = wave * 32 + i * 16 + q4 * 4 + r;
        go[(size_t)row * 1024 + j * 16 + n16] = (bf16_t)(oacc[i][j][r] * invs[i][r]);
      }
}

// ---------------------------------------------------------------------------
extern "C" void kernel_launch(void* const* d_in, const int* in_sizes, int n_in,
                              void* d_out, int out_size, void* d_ws, size_t ws_size,
                              hipStream_t stream) {
  const float* x    = (const float*)d_in[0];
  const float* Win  = (const float*)d_in[1];   // [3072,1024]
  const float* bin  = (const float*)d_in[2];   // [3072]
  const float* Wout = (const float*)d_in[3];   // [1024,1024]
  const float* bout = (const float*)d_in[4];   // [1024]
  float* out = (float*)d_out;

  const size_t M = 16384, H = 1024, H3 = 3072;

  // workspace layout (~72 MB): xb | Wpk | Woutb | ob
  bf16_t* xb    = (bf16_t*)d_ws;        // M*H
  bf16_t* Wpk   = xb + M * H;           // H3*H (head-packed)
  bf16_t* Woutb = Wpk + H3 * H;         // H*H
  bf16_t* ob    = Woutb + H * H;        // M*H

  // one fused conversion dispatch: 2,621,440 8-elem chunks / 256 = 10240 blocks
  cvt_all<<<dim3(10240), 256, 0, stream>>>(x, Win, Wout, xb, Wpk, Woutb);

  // grid: window-major -> linear id = wid + 128*h -> window pins to XCD wid%8,
  // all 16 heads of a window share that XCD's L2 copy of X.
  qkv_attn<<<dim3(128, 16), 256, 0, stream>>>(xb, Wpk, bin, ob);

  // 512 blocks = one full dispatch round at 2/CU; XCD id%8 pins one B-tile.
  gemm_out<<<dim3((unsigned)(H / 256), (unsigned)(M / 128)), 256, 0, stream>>>(
      ob, Woutb, bout, out, (int)M, (int)H, (int)H);
}